// Round 13
// baseline (297.942 us; speedup 1.0000x reference)
//
#include <hip/hip_runtime.h>
#include <hip/hip_bf16.h>

typedef unsigned short u16;
typedef __bf16 bf16x8 __attribute__((ext_vector_type(8)));
typedef __bf16 bf16x4 __attribute__((ext_vector_type(4)));
typedef u16 u16x8 __attribute__((ext_vector_type(8)));
typedef float f32x4 __attribute__((ext_vector_type(4)));
typedef float f32x16 __attribute__((ext_vector_type(16)));

__device__ __forceinline__ u16 f2bf(float f) {
    unsigned u = __float_as_uint(f);
    return (u16)((u + 0x7fffu + ((u >> 16) & 1u)) >> 16);
}
__device__ __forceinline__ unsigned pkbf2(float a, float b) {
    __hip_bfloat162 h = __float22bfloat162_rn(make_float2(a, b));
    return *(unsigned*)&h;
}

// async global->LDS, 16B per lane, LDS dest = wave-uniform base + lane*16
__device__ __forceinline__ void gload16(const u16* g, u16* l) {
    __builtin_amdgcn_global_load_lds(
        (const __attribute__((address_space(1))) void*)g,
        (__attribute__((address_space(3))) void*)l, 16, 0, 0);
}

// raw barrier with compile-time scheduling fence (no vmcnt drain!)
__device__ __forceinline__ void block_sync() {
    __builtin_amdgcn_sched_barrier(0);
    __builtin_amdgcn_s_barrier();
    __builtin_amdgcn_sched_barrier(0);
}
template<int N> __device__ __forceinline__ void waitvm() {
    if constexpr (N == 0)      asm volatile("s_waitcnt vmcnt(0)" ::: "memory");
    else if constexpr (N == 3) asm volatile("s_waitcnt vmcnt(3)" ::: "memory");
    else if constexpr (N == 4) asm volatile("s_waitcnt vmcnt(4)" ::: "memory");
    else if constexpr (N == 6) asm volatile("s_waitcnt vmcnt(6)" ::: "memory");
    else                       asm volatile("s_waitcnt vmcnt(8)" ::: "memory");
}

// ---------------- fp32 -> bf16 convert (x, wqkv, wo fused in one launch) ----
#define CVT_N1 2097152
#define CVT_N2 3670016
#define CVT_TOT 4718592
__global__ void cvt_all(const float* __restrict__ x, const float* __restrict__ wqkv,
                        const float* __restrict__ wo, u16* __restrict__ xb,
                        u16* __restrict__ wqkvb, u16* __restrict__ wob) {
    for (int i = blockIdx.x * 256 + threadIdx.x; i < CVT_TOT; i += 4608 * 256) {
        const float* s; u16* d; int j;
        if (i < CVT_N1)      { s = x;    d = xb;    j = i; }
        else if (i < CVT_N2) { s = wqkv; d = wqkvb; j = i - CVT_N1; }
        else                 { s = wo;   d = wob;   j = i - CVT_N2; }
        float4 v = *(const float4*)(s + (size_t)j * 4);
        uint2 o; o.x = pkbf2(v.x, v.y); o.y = pkbf2(v.z, v.w);
        *(uint2*)(d + (size_t)j * 4) = o;
    }
}

// ---------------- GEMM core v3: BK=32, 3 LDS buffers, ONE barrier/K-tile ----
// 72 KB LDS at 128x256 -> 2 blocks/CU; co-resident block hides stalls.
template<int ROWS>
__device__ __forceinline__ void stage32(const u16* __restrict__ g, int K,
                                        int k0, u16* l, int tid) {
#pragma unroll
    for (int s = 0; s < ROWS / 128; ++s) {
        int row = s * 128 + (tid >> 2);
        int sc = (tid & 3) ^ ((tid >> 2) & 3);
        gload16(g + (size_t)row * K + k0 + sc * 8, l + s * 4096 + tid * 8);
    }
}

template<int BM, int BN>
__device__ __forceinline__ void gemm_pipeline(const u16* __restrict__ Ab,
                                              const u16* __restrict__ Bb, int K,
                                              u16* sAll,
                                              f32x4 (&acc)[BM / 32][BN / 64],
                                              int tid) {
    constexpr int MR = BM / 32, NR = BN / 64;
    constexpr int TILE = (BM + BN) * 32;      // elems per buffer
    constexpr int NLD = (BM + BN) / 128;      // gload16 per wave per tile
    const int lane = tid & 63, wave = tid >> 6;
    const int quad = lane >> 4, l16 = lane & 15;
    const int wm = wave >> 2, wn = wave & 3;
    const int ar0 = wm * (BM / 2) + l16;
    const int br0 = wn * (BN / 4) + l16;

    // prologue: tiles 0,1 -> bufs 0,1
    stage32<BM>(Ab, K, 0, sAll, tid);
    stage32<BN>(Bb, K, 0, sAll + BM * 32, tid);
    stage32<BM>(Ab, K, 32, sAll + TILE, tid);
    stage32<BN>(Bb, K, 32, sAll + TILE + BM * 32, tid);

    const int nt = K >> 5;
    int bufc = 0, bufn = 2;
    for (int t = 0; t < nt; ++t) {
        if (t < nt - 1) waitvm<NLD>();   // tile t landed; t+1 stays in flight
        else            waitvm<0>();
        block_sync();                    // publish tile t; buf (t-1)%3 is free
        if (t + 2 < nt) {
            u16* nb = sAll + bufn * TILE;
            stage32<BM>(Ab, K, (t + 2) * 32, nb, tid);
            stage32<BN>(Bb, K, (t + 2) * 32, nb + BM * 32, tid);
        }
        const u16* cA = sAll + bufc * TILE;
        const u16* cB = cA + BM * 32;
        bf16x8 af[MR], bf[NR];
#pragma unroll
        for (int m = 0; m < MR; ++m) {
            int r = ar0 + m * 16;
            af[m] = *(const bf16x8*)&cA[r * 32 + ((quad ^ (r & 3)) * 8)];
        }
#pragma unroll
        for (int n = 0; n < NR; ++n) {
            int r = br0 + n * 16;
            bf[n] = *(const bf16x8*)&cB[r * 32 + ((quad ^ (r & 3)) * 8)];
        }
        __builtin_amdgcn_s_setprio(1);
#pragma unroll
        for (int m = 0; m < MR; ++m)
#pragma unroll
            for (int n = 0; n < NR; ++n)
                acc[m][n] = __builtin_amdgcn_mfma_f32_16x16x32_bf16(
                    af[m], bf[n], acc[m][n], 0, 0, 0);
        __builtin_amdgcn_s_setprio(0);
        bufc = (bufc == 2) ? 0 : bufc + 1;
        bufn = (bufn == 2) ? 0 : bufn + 1;
    }
}

// ---------------- o-proj GEMM: C = A * B^T, fp32 out (128x256 tile) ---------
__global__ __launch_bounds__(512, 2)
void gemm_bt(const u16* __restrict__ A, const u16* __restrict__ B,
             float* __restrict__ C, int M, int N, int K) {
    __shared__ u16 sAll[3 * (128 + 256) * 32];   // 72 KB -> 2 blocks/CU
    const int tid = threadIdx.x;
    const int wave = tid >> 6, lane = tid & 63;
    const int quad = lane >> 4, l16 = lane & 15;
    const int wm = wave >> 2, wn = wave & 3;
    const int bid = blockIdx.x;
    const int xcd = bid & 7, r2 = bid >> 3;          // r2 in [0,32)
    const int bni = (xcd & 1) * 4 + (r2 & 3);        // [0,8)
    const int bmi = (xcd >> 1) * 8 + (r2 >> 2);      // [0,32)
    const size_t bm = (size_t)bmi * 128, bn = (size_t)bni * 256;
    f32x4 acc[4][4] = {};
    gemm_pipeline<128, 256>(A + bm * K, B + bn * K, K, sAll, acc, tid);
#pragma unroll
    for (int m = 0; m < 4; ++m)
#pragma unroll
        for (int n = 0; n < 4; ++n)
#pragma unroll
            for (int r = 0; r < 4; ++r)
                C[(bm + wm * 64 + m * 16 + quad * 4 + r) * (size_t)N +
                  bn + wn * 64 + n * 16 + l16] = acc[m][n][r];
}

// ---------------- fused QKV GEMM (128x256): RMSNorm+RoPE (q,k) / transpose (v)
// 128x256 tile -> 72 KB LDS, 2 blocks/CU, grid 384 (fills all 256 CUs).
// bx: 0..7 = Q head-pairs, 8..9 = K, 10..11 = V. V stored KEY-PERMUTED
// (sigma = swap bits2,3 of seq%16) so flash PV needs no P exchange.
__global__ __launch_bounds__(512, 2)
void gemm_qkv(const u16* __restrict__ xb, const u16* __restrict__ wq,
              const float* __restrict__ qw, const float* __restrict__ kw,
              const float* __restrict__ fcos, const float* __restrict__ fsin,
              u16* __restrict__ qb, u16* __restrict__ kb, u16* __restrict__ vt) {
    __shared__ u16 sAll[3 * (128 + 256) * 32];   // 72 KB
    const int tid = threadIdx.x;
    const int wave = tid >> 6, lane = tid & 63;
    const int quad = lane >> 4, l16 = lane & 15;
    const int wm = wave >> 2, wn = wave & 3;
    const int bid = blockIdx.x;
    const int xcd = bid & 7, r2 = bid >> 3;          // r2 in [0,48)
    const int bx = (xcd & 1) * 6 + r2 % 6;           // [0,12)
    const int by = (xcd >> 1) * 8 + r2 / 6;          // [0,32)
    f32x4 acc[4][4] = {};
    gemm_pipeline<128, 256>(xb + (size_t)by * 128 * 2048,
                            wq + (size_t)bx * 256 * 2048, 2048, sAll, acc, tid);

    const int b = by >> 4;                       // batch
    const int sb = (by & 15) * 128 + wm * 64;    // seq base (+m*16+quad*4+r)
    const int headh = wn >> 1;                   // which head of the 2 in tile
    const int dcol0 = (wn & 1) * 64;             // dim base within head

    if (bx >= 10) {
        // V: bf16 transpose store, sigma-permuted quad (1<->2)
        const int qp = ((quad & 1) << 1) | (quad >> 1);
        const int kvh = (bx - 10) * 2 + headh;
        u16* base = vt + (size_t)(b * 4 + kvh) * 128 * 2048;
#pragma unroll
        for (int m = 0; m < 4; ++m) {
            int s0 = sb + m * 16 + qp * 4;
#pragma unroll
            for (int n = 0; n < 4; ++n) {
                int d = dcol0 + n * 16 + l16;
                bf16x4 pv;
#pragma unroll
                for (int r = 0; r < 4; ++r) pv[r] = (__bf16)acc[m][n][r];
                *(bf16x4*)(base + (size_t)d * 2048 + s0) = pv;
            }
        }
        return;
    }

    // Q/K: RMSNorm + RoPE. red[(parity*2+headh)][row(128)]
    float* red = (float*)sAll;
    float ssq[4][4];
#pragma unroll
    for (int m = 0; m < 4; ++m)
#pragma unroll
        for (int r = 0; r < 4; ++r) {
            float t = 0.f;
#pragma unroll
            for (int n = 0; n < 4; ++n) t += acc[m][n][r] * acc[m][n][r];
#pragma unroll
            for (int off = 1; off <= 8; off <<= 1) t += __shfl_xor(t, off);
            ssq[m][r] = t;
        }
    __syncthreads();
    if (l16 == 0)
#pragma unroll
        for (int m = 0; m < 4; ++m)
#pragma unroll
            for (int r = 0; r < 4; ++r)
                red[((wn & 1) * 2 + headh) * 128 + wm * 64 + m * 16 + quad * 4 + r] =
                    ssq[m][r];
    __syncthreads();

    const bool isQ = bx < 8;
    const float qscl = isQ ? 0.08838834764831845f * 1.4426950408889634f : 1.0f;
    const float* wp = isQ ? qw : kw;
    float wcol[4];
#pragma unroll
    for (int n = 0; n < 4; ++n) wcol[n] = wp[dcol0 + n * 16 + l16];
    u16* dstbase = isQ ? qb + (size_t)(b * 16 + bx * 2 + headh) * 2048 * 128
                       : kb + (size_t)(b * 4 + (bx - 8) * 2 + headh) * 2048 * 128;
    const float sgn = (l16 & 1) ? 1.f : -1.f;

#pragma unroll
    for (int m = 0; m < 4; ++m) {
#pragma unroll
        for (int r = 0; r < 4; ++r) {
            int rowl = wm * 64 + m * 16 + quad * 4 + r;
            float var = (red[headh * 128 + rowl] +
                         red[(2 + headh) * 128 + rowl]) * (1.0f / 128.0f);
            float rms = rsqrtf(var + 1.1920928955078125e-07f) * qscl;
            int s = sb + m * 16 + quad * 4 + r;
            const float* fc = fcos + (size_t)s * 128 + dcol0;
            const float* fn = fsin + (size_t)s * 128 + dcol0;
            u16* drow = dstbase + (size_t)s * 128 + dcol0;
#pragma unroll
            for (int n = 0; n < 4; ++n) {
                float y = acc[m][n][r] * rms * wcol[n];
                float yp = __shfl_xor(y, 1);
                float o = y * fc[n * 16 + l16] + sgn * yp * fn[n * 16 + l16];
                drow[n * 16 + l16] = f2bf(o);
            }
        }
    }
}

// ---------------- flash attention v5: K dbuf + V single-buf, 3 blocks/CU ----
#define KBUF(c) ((c) * 8192)
#define VBUF 16384
__global__ __launch_bounds__(256, 3)
void flash_attn(const u16* __restrict__ qb, const u16* __restrict__ kb,
                const u16* __restrict__ vt, u16* __restrict__ ab) {
    __shared__ u16 smem[24576];
    __shared__ float Llds[128];

    const int tid = threadIdx.x;
    const int wave = tid >> 6, lane = tid & 63;
    const int hf = lane >> 5, c32 = lane & 31;
    const int bid = blockIdx.x;
    const int swz = (bid & 7) * 64 + (bid >> 3);
    const int qt = swz & 15, bh = swz >> 4;
    const int hh = bh & 15, bb = bh >> 4;
    const int kh = hh >> 2;

    const u16* Qbase = qb + (size_t)(bb * 16 + hh) * 2048 * 128;
    const u16* Kbase = kb + (size_t)(bb * 4 + kh) * 2048 * 128;
    const u16* Vbase = vt + (size_t)(bb * 4 + kh) * 128 * 2048;

    bf16x8 aq[8];
#pragma unroll
    for (int kq = 0; kq < 8; ++kq)
        aq[kq] = *(const bf16x8*)(Qbase +
            (size_t)(qt * 128 + wave * 32 + c32) * 128 + kq * 16 + hf * 8);

    f32x16 O[4] = {};
    float lacc = 0.f;

    const int krow = tid >> 4;
    const u16* kg = Kbase + (size_t)krow * 128 + (((tid & 15) ^ (krow & 7)) * 8);
    const int vrow = tid >> 3;
    const u16* vg = Vbase + (size_t)vrow * 2048 + (((tid & 7) ^ (vrow & 7)) * 8);

    auto stageK = [&](int buf, int key0) {
#pragma unroll
        for (int s = 0; s < 4; ++s)
            gload16(kg + key0 * 128 + s * 2048, &smem[KBUF(buf) + s * 2048 + tid * 8]);
    };
    auto stageV = [&](int key0) {
#pragma unroll
        for (int s = 0; s < 4; ++s)
            gload16(vg + (size_t)s * 65536 + key0, &smem[VBUF + s * 2048 + tid * 8]);
    };

    stageK(0, 0);
    stageV(0);

    for (int kt = 0; kt < 32; ++kt) {
        const int cur = kt & 1;
        if (kt < 31) {
            stageK(cur ^ 1, (kt + 1) * 64);
            waitvm<8>();               // K(kt)+V(kt) landed; K(kt+1) in flight
        } else {
            waitvm<0>();
        }
        block_sync();                  // B1: publish K(kt)

        f32x16 sc[2] = {};
        __builtin_amdgcn_s_setprio(1);
#pragma unroll
        for (int kq = 0; kq < 8; ++kq) {
#pragma unroll
            for (int mt = 0; mt < 2; ++mt) {
                bf16x8 kf = *(const bf16x8*)&smem[KBUF(cur) + (mt * 32 + c32) * 128 +
                                                 (((kq * 2 + hf) ^ (c32 & 7)) * 8)];
                sc[mt] = __builtin_amdgcn_mfma_f32_32x32x16_bf16(kf, aq[kq], sc[mt], 0, 0, 0);
            }
        }
        __builtin_amdgcn_s_setprio(0);

        int pdw[2][8];
#pragma unroll
        for (int mt = 0; mt < 2; ++mt) {
            float p[16];
#pragma unroll
            for (int r = 0; r < 16; ++r) p[r] = __builtin_amdgcn_exp2f(sc[mt][r]);
            float a0 = (p[0] + p[1]) + (p[2] + p[3]);
            float a1 = (p[4] + p[5]) + (p[6] + p[7]);
            float a2 = (p[8] + p[9]) + (p[10] + p[11]);
            float a3 = (p[12] + p[13]) + (p[14] + p[15]);
            lacc += (a0 + a1) + (a2 + a3);
#pragma unroll
            for (int i = 0; i < 8; ++i) pdw[mt][i] = (int)pkbf2(p[2 * i], p[2 * i + 1]);
        }

        if (kt < 31) waitvm<4>();      // V(kt) landed; K(kt+1) stays in flight
        else         waitvm<0>();
        block_sync();                  // B2: publish V(kt)

        __builtin_amdgcn_s_setprio(1);
#pragma unroll
        for (int kc = 0; kc < 4; ++kc) {
            const int mt = kc >> 1, L = kc & 1;
            union { int i[4]; bf16x8 v; } u;
            u.i[0] = pdw[mt][4 * L + 0];
            u.i[1] = pdw[mt][4 * L + 1];
            u.i[2] = pdw[mt][4 * L + 2];
            u.i[3] = pdw[mt][4 * L + 3];
#pragma unroll
            for (int dt = 0; dt < 4; ++dt) {
                bf16x8 vf = *(const bf16x8*)&smem[VBUF + (dt * 32 + c32) * 64 +
                                                 (((kc * 2 + hf) ^ (c32 & 7)) * 8)];
                O[dt] = __builtin_amdgcn_mfma_f32_32x32x16_bf16(u.v, vf, O[dt], 0, 0, 0);
            }
        }
        __builtin_amdgcn_s_setprio(0);
        block_sync();                  // B3: all V reads done -> V buf free
        if (kt < 31) stageV((kt + 1) * 64);
    }

    float l = lacc + __shfl_xor(lacc, 32);
    if (hf == 0) Llds[wave * 32 + c32] = l;

    float inv[16];
#pragma unroll
    for (int r = 0; r < 16; ++r)
        inv[r] = __builtin_amdgcn_rcpf(Llds[wave * 32 + (r & 3) + 8 * (r >> 2) + 4 * hf]);

    u16* scr = &smem[wave * 32 * 136];
#pragma unroll
    for (int dt = 0; dt < 4; ++dt)
#pragma unroll
        for (int r = 0; r < 16; ++r) {
            int q_r = (r & 3) + 8 * (r >> 2) + 4 * hf;
            scr[q_r * 136 + dt * 32 + c32] = f2bf(O[dt][r] * inv[r]);
        }
#pragma unroll
    for (int it = 0; it < 8; ++it) {
        int f = it * 64 + lane;
        int row = f >> 4, c = f & 15;
        u16x8 v = *(const u16x8*)&scr[row * 136 + c * 8];
        int qg = qt * 128 + wave * 32 + row;
        *(u16x8*)(ab + ((size_t)(bb * 2048 + qg)) * 2048 + hh * 128 + c * 8) = v;
    }
}

// ---------------- host launch ----------------
extern "C" void kernel_launch(void* const* d_in, const int* in_sizes, int n_in,
                              void* d_out, int out_size, void* d_ws, size_t ws_size,
                              hipStream_t stream) {
    const float* x    = (const float*)d_in[0];
    const float* wqkv = (const float*)d_in[1];
    const float* wo   = (const float*)d_in[2];
    const float* qw   = (const float*)d_in[3];
    const float* kw   = (const float*)d_in[4];
    const float* fc   = (const float*)d_in[5];
    const float* fs   = (const float*)d_in[6];
    float* out = (float*)d_out;
    char* ws = (char*)d_ws;

    u16* xb    = (u16*)(ws + 0);          // 4096x2048 bf16 (16 MB)
    u16* wqkvb = (u16*)(ws + 16777216);   // 3072x2048 bf16 (12 MB)
    u16* wob   = (u16*)(ws + 29360128);   // 2048x2048 bf16 ( 8 MB)
    u16* qb    = (u16*)(ws + 37748736);   // [2,16,2048,128] (16 MB)
    u16* kb    = (u16*)(ws + 54525952);   // [2,4,2048,128]  ( 4 MB)
    u16* vt    = (u16*)(ws + 58720256);   // [2,4,128,2048]  ( 4 MB, key-permuted)
    u16* ab    = (u16*)(ws + 62914560);   // 4096x2048 bf16  (16 MB)

    cvt_all<<<4608, 256, 0, stream>>>(x, wqkv, wo, xb, wqkvb, wob);
    gemm_qkv<<<384, 512, 0, stream>>>(xb, wqkvb, qw, kw, fc, fs, qb, kb, vt);
    flash_attn<<<512, 256, 0, stream>>>(qb, kb, vt, ab);
    gemm_bt<<<256, 512, 0, stream>>>(ab, wob, out, 4096, 2048, 2048);
}